// Round 17
// baseline (541.270 us; speedup 1.0000x reference)
//
#include <hip/hip_runtime.h>
#include <hip/hip_bf16.h>
#include <stdint.h>

#define BATCH   32
#define SEQ     512
#define DMODEL  128
#define NHEADS  8
#define DHEAD   64
#define NEGV    -1e9f

using f32x4 = __attribute__((ext_vector_type(4))) float;
using s16x8 = __attribute__((ext_vector_type(8))) short;
using u16x4 = __attribute__((ext_vector_type(4))) unsigned short;
using u16x8 = __attribute__((ext_vector_type(8))) unsigned short;

__device__ __forceinline__ unsigned short f2bf(float f) {
    union { float f; unsigned int i; } w; w.f = f;
    unsigned int u = w.i;
    u += 0x7fffu + ((u >> 16) & 1u);   // RNE
    return (unsigned short)(u >> 16);
}
__device__ __forceinline__ float bf2f(unsigned short u) {
    union { unsigned int i; float f; } w; w.i = ((unsigned int)u) << 16; return w.f;
}
__device__ __forceinline__ s16x8 fragf(const float* p0, const float* p1) {
    float4 a = *reinterpret_cast<const float4*>(p0);
    float4 b = *reinterpret_cast<const float4*>(p1);
    union { s16x8 v; unsigned short e[8]; } u;
    u.e[0] = f2bf(a.x); u.e[1] = f2bf(a.y); u.e[2] = f2bf(a.z); u.e[3] = f2bf(a.w);
    u.e[4] = f2bf(b.x); u.e[5] = f2bf(b.y); u.e[6] = f2bf(b.z); u.e[7] = f2bf(b.w);
    return u.v;
}
__device__ __forceinline__ s16x8 frag8(const unsigned short* p0, const unsigned short* p1) {
    union { s16x8 v; u16x4 h[2]; } u;
    u.h[0] = *reinterpret_cast<const u16x4*>(p0);
    u.h[1] = *reinterpret_cast<const u16x4*>(p1);
    return u.v;
}
__device__ __forceinline__ s16x8 lds_frag(const unsigned short* row_base, int col0, int swz) {
    union { s16x8 v; u16x4 h[2]; } u;
    u.h[0] = *reinterpret_cast<const u16x4*>(row_base + ((col0) ^ swz));
    u.h[1] = *reinterpret_cast<const u16x4*>(row_base + ((col0 + 16) ^ swz));
    return u.v;
}

// ---------------- Kernel 0: fused wtrans + mask bitpack ----------------
// blocks 0..2047: bitpack; blocks 2048..2055: W_fc transpose; 2056..2063: W_Q transpose.
__global__ void prep_kernel(const int* __restrict__ mask, unsigned long long* __restrict__ bits,
                            const float* __restrict__ wfc, const float* __restrict__ wq,
                            unsigned short* __restrict__ Wtfc, unsigned short* __restrict__ WQt) {
    const int blk = blockIdx.x;
    if (blk < 2048) {
        const int wave = threadIdx.x >> 6, lane = threadIdx.x & 63;
        const int wid0 = (blk * 4 + wave) * 16;
#pragma unroll
        for (int i = 0; i < 16; i++) {
            const int w = wid0 + i;
            int v = mask[(size_t)w * 64 + lane];
            unsigned long long bb = __ballot(v != 0);
            if (lane == 0) bits[w] = bb;
        }
    } else if (blk < 2056) {
        const int i0 = (blk - 2048) * 8192;
        for (int i = i0 + threadIdx.x; i < i0 + 8192; i += 256) {
            int k = i >> 7, n = i & 127;
            Wtfc[(size_t)n * 512 + k] = f2bf(wfc[i]);
        }
    } else {
        const int i0 = (blk - 2056) * 8192;
        for (int i = i0 + threadIdx.x; i < i0 + 8192; i += 256) {
            int k = i >> 9, n = i & 511;
            WQt[(size_t)n * 128 + k] = f2bf(wq[i]);
        }
    }
}

// ---------------- Kernel 1: K/V projection into ws, MFMA-fragment-permuted ----------------
// Kp layout: [bh][kt 0..31][f 0..1][lane 0..63][8]  (consumer QK A-frag = one 16B load)
// Vt layout: [bh][kk 0..15][dt 0..3][lane 0..63][8] (consumer PV B-frag = one 16B load)
__global__ __launch_bounds__(512, 2) void proj_kernel(
    const float* __restrict__ inK, const float* __restrict__ inV,
    const float* __restrict__ WK, const float* __restrict__ WV,
    unsigned short* __restrict__ Kp, unsigned short* __restrict__ Vt) {
    __shared__ unsigned short Wt[64 * 128];
    const int tid = threadIdx.x;
    const int lane = tid & 63;
    const int wave = tid >> 6;
    const int g = lane >> 4, c = lane & 15;
    const int bh = blockIdx.x;
    const int b = bh >> 3, h = bh & 7;
    const int col0 = 4 * g;
    const int vmode = blockIdx.y;
    const float* X = vmode ? inV : inK;
    const float* W = vmode ? WV : WK;

    for (int i = tid; i < 8192; i += 512) {
        int k = i >> 6, d = i & 63;
        Wt[d * 128 + (k ^ ((d & 7) << 3))] = f2bf(W[(size_t)k * 512 + h * 64 + d]);
    }
    __syncthreads();

    f32x4 a4[4][4];   // [st][dt]
#pragma unroll
    for (int st = 0; st < 4; st++)
#pragma unroll
        for (int dt = 0; dt < 4; dt++) a4[st][dt] = f32x4{0.f, 0.f, 0.f, 0.f};
#pragma unroll
    for (int ks = 0; ks < 4; ks++) {
        s16x8 xf[4], wt[4];
#pragma unroll
        for (int st = 0; st < 4; st++) {
            const float* p = X + (size_t)(b * 512 + wave * 64 + st * 16 + c) * 128 + ks * 32 + col0;
            xf[st] = fragf(p, p + 16);
        }
#pragma unroll
        for (int dt = 0; dt < 4; dt++) {
            int row = dt * 16 + c;
            wt[dt] = lds_frag(Wt + row * 128, ks * 32 + col0, (row & 7) << 3);
        }
        if (!vmode) {
#pragma unroll
            for (int st = 0; st < 4; st++)
#pragma unroll
                for (int dt = 0; dt < 4; dt++)
                    a4[st][dt] = __builtin_amdgcn_mfma_f32_16x16x32_bf16(wt[dt], xf[st], a4[st][dt], 0, 0, 0);
        } else {
#pragma unroll
            for (int st = 0; st < 4; st++)
#pragma unroll
                for (int dt = 0; dt < 4; dt++)
                    a4[st][dt] = __builtin_amdgcn_mfma_f32_16x16x32_bf16(xf[st], wt[dt], a4[st][dt], 0, 0, 0);
        }
    }
    if (!vmode) {
#pragma unroll
        for (int st = 0; st < 4; st++) {
            const int kt = wave * 4 + st;
#pragma unroll
            for (int f = 0; f < 2; f++) {
                u16x8 o;
#pragma unroll
                for (int j = 0; j < 4; j++) {
                    o[j]     = f2bf(a4[st][2 * f][j]);
                    o[4 + j] = f2bf(a4[st][2 * f + 1][j]);
                }
                *reinterpret_cast<u16x8*>(Kp + ((size_t)(bh * 32 + kt) * 2 + f) * 512 + lane * 8) = o;
            }
        }
    } else {
#pragma unroll
        for (int p = 0; p < 2; p++) {
            const int kk = wave * 2 + p;
#pragma unroll
            for (int dt = 0; dt < 4; dt++) {
                u16x8 o;
#pragma unroll
                for (int j = 0; j < 4; j++) {
                    o[j]     = f2bf(a4[2 * p][dt][j]);
                    o[4 + j] = f2bf(a4[2 * p + 1][dt][j]);
                }
                *reinterpret_cast<u16x8*>(Vt + ((size_t)(bh * 16 + kk) * 4 + dt) * 512 + lane * 8) = o;
            }
        }
    }
}

// ---------------- Kernel 2: attention, LDS-staged K/V, per-bh block ----------------
// grid 256 (= 1 block/CU): block = one bh; 512 threads = 8 waves; each wave does 4 q-groups of 16 q.
// K/V staged once into 128KB LDS (fragment layout is linear-in-lane), one barrier, then barrier-free.
__global__ __launch_bounds__(512, 2) void attn_kernel(
    const float* __restrict__ inQ,            // [b*512][128] fp32
    const unsigned short* __restrict__ WQt,   // [512][128] bf16 (W_Q^T)
    const unsigned short* __restrict__ Kp,    // [bh][kt][f][lane][8] bf16
    const unsigned short* __restrict__ Vt,    // [bh][kk][dt][lane][8] bf16
    const unsigned long long* __restrict__ mbits,
    float* __restrict__ attn_out,             // [bh][q][k] fp32
    unsigned short* __restrict__ ctx) {       // [b*512][512] bf16
    __shared__ unsigned short Klds[32768];    // 64KB
    __shared__ unsigned short Vlds[32768];    // 64KB
    const int tid = threadIdx.x;
    const int lane = tid & 63;
    const int wave = tid >> 6;          // 0..7
    const int g = lane >> 4, c = lane & 15;
    const int col0 = 4 * g;
    const int bid = blockIdx.x;
    // XCD swizzle: XCD x owns bh x*32..x*32+31 (4 consecutive b, all heads)
    const int bh = ((bid & 7) << 5) + (bid >> 3);
    const int b = bh >> 3, h = bh & 7;

    // ---- stage K/V fragments into LDS (coalesced 16B/lane) ----
    {
        const unsigned short* Kb = Kp + (size_t)bh * 32768;
        const unsigned short* Vb = Vt + (size_t)bh * 32768;
        for (int i = tid; i < 4096; i += 512) {
            *reinterpret_cast<u16x8*>(&Klds[i * 8]) = *reinterpret_cast<const u16x8*>(Kb + (size_t)i * 8);
            *reinterpret_cast<u16x8*>(&Vlds[i * 8]) = *reinterpret_cast<const u16x8*>(Vb + (size_t)i * 8);
        }
    }
    __syncthreads();

    // ---- 4 q-groups per wave; fully independent after the barrier ----
    for (int t = 0; t < 4; t++) {
        const int gi = t * 8 + wave;        // q-group 0..31
        const int qg = gi * 16 + c;         // this lane's q row

        // mask bits for this q-row
        union { uint4 q[4]; unsigned short e[32]; } mb;
        {
            const unsigned short* mrow16 = (const unsigned short*)(mbits + ((size_t)b * 512 + qg) * 8);
            mb.q[0] = *reinterpret_cast<const uint4*>(mrow16);
            mb.q[1] = *reinterpret_cast<const uint4*>(mrow16 + 8);
            mb.q[2] = *reinterpret_cast<const uint4*>(mrow16 + 16);
            mb.q[3] = *reinterpret_cast<const uint4*>(mrow16 + 24);
        }

        // Q projection (global WQt, L2-hot)
        f32x4 qa[4];
#pragma unroll
        for (int dt = 0; dt < 4; dt++) qa[dt] = f32x4{0.f, 0.f, 0.f, 0.f};
        const float* Xq = inQ + ((size_t)b * 512 + qg) * 128;
#pragma unroll
        for (int ks = 0; ks < 4; ks++) {
            s16x8 xq = fragf(Xq + ks * 32 + col0, Xq + ks * 32 + col0 + 16);
#pragma unroll
            for (int dt = 0; dt < 4; dt++) {
                const unsigned short* wp = WQt + (size_t)(h * 64 + dt * 16 + c) * 128 + ks * 32 + col0;
                s16x8 wt = frag8(wp, wp + 16);
                qa[dt] = __builtin_amdgcn_mfma_f32_16x16x32_bf16(wt, xq, qa[dt], 0, 0, 0);
            }
        }
        s16x8 qf0, qf1;
        {
            union { s16x8 v; u16x4 h2[2]; } q0, q1;
#pragma unroll
            for (int j = 0; j < 4; j++) {
                q0.h2[0][j] = f2bf(qa[0][j]);
                q0.h2[1][j] = f2bf(qa[1][j]);
                q1.h2[0][j] = f2bf(qa[2][j]);
                q1.h2[1][j] = f2bf(qa[3][j]);
            }
            qf0 = q0.v; qf1 = q1.v;
        }

        // S^T = K * Q^T — fragments from LDS (ds_read_b128, 2-way free)
        f32x4 acc[32];
#pragma unroll
        for (int kt = 0; kt < 32; kt++) acc[kt] = f32x4{0.f, 0.f, 0.f, 0.f};
#pragma unroll
        for (int kt = 0; kt < 32; kt++) {
            s16x8 a0 = *reinterpret_cast<const s16x8*>(&Klds[(kt * 2 + 0) * 512 + lane * 8]);
            s16x8 a1 = *reinterpret_cast<const s16x8*>(&Klds[(kt * 2 + 1) * 512 + lane * 8]);
            acc[kt] = __builtin_amdgcn_mfma_f32_16x16x32_bf16(a0, qf0, acc[kt], 0, 0, 0);
            acc[kt] = __builtin_amdgcn_mfma_f32_16x16x32_bf16(a1, qf1, acc[kt], 0, 0, 0);
        }

        // scale + mask + row max
        float m = -3.0e38f;
#pragma unroll
        for (int kt = 0; kt < 32; kt++) {
            const unsigned nib = ((unsigned)mb.e[kt]) >> col0;
            float s0 = (nib & 1u) ? NEGV : acc[kt][0] * 0.125f;
            float s1 = (nib & 2u) ? NEGV : acc[kt][1] * 0.125f;
            float s2 = (nib & 4u) ? NEGV : acc[kt][2] * 0.125f;
            float s3 = (nib & 8u) ? NEGV : acc[kt][3] * 0.125f;
            acc[kt] = f32x4{s0, s1, s2, s3};
            m = fmaxf(m, fmaxf(fmaxf(s0, s1), fmaxf(s2, s3)));
        }
        m = fmaxf(m, __shfl_xor(m, 16));
        m = fmaxf(m, __shfl_xor(m, 32));

        float sum = 0.f;
#pragma unroll
        for (int kt = 0; kt < 32; kt++) {
#pragma unroll
            for (int j = 0; j < 4; j++) {
                float e = __expf(acc[kt][j] - m);
                acc[kt][j] = e;
                sum += e;
            }
        }
        sum += __shfl_xor(sum, 16);
        sum += __shfl_xor(sum, 32);
        const float inv = 1.0f / sum;

        float* arow = attn_out + ((size_t)bh * 512 + qg) * 512;
        f32x4 cacc[4];
#pragma unroll
        for (int dt = 0; dt < 4; dt++) cacc[dt] = f32x4{0.f, 0.f, 0.f, 0.f};

#pragma unroll
        for (int kk = 0; kk < 16; kk++) {
            f32x4 flo, fhi;
#pragma unroll
            for (int j = 0; j < 4; j++) {
                flo[j] = acc[2 * kk][j] * inv;
                fhi[j] = acc[2 * kk + 1][j] * inv;
            }
            *reinterpret_cast<f32x4*>(arow + kk * 32 + col0)      = flo;
            *reinterpret_cast<f32x4*>(arow + kk * 32 + 16 + col0) = fhi;

            union { s16x8 v; unsigned short e[8]; } pf;
            pf.e[0] = f2bf(flo[0]); pf.e[1] = f2bf(flo[1]); pf.e[2] = f2bf(flo[2]); pf.e[3] = f2bf(flo[3]);
            pf.e[4] = f2bf(fhi[0]); pf.e[5] = f2bf(fhi[1]); pf.e[6] = f2bf(fhi[2]); pf.e[7] = f2bf(fhi[3]);
#pragma unroll
            for (int dt = 0; dt < 4; dt++) {
                s16x8 vf = *reinterpret_cast<const s16x8*>(&Vlds[(kk * 4 + dt) * 512 + lane * 8]);
                cacc[dt] = __builtin_amdgcn_mfma_f32_16x16x32_bf16(pf.v, vf, cacc[dt], 0, 0, 0);
            }
        }

        unsigned short* crow = ctx + ((size_t)b * 512 + gi * 16) * 512 + h * 64;
#pragma unroll
        for (int dt = 0; dt < 4; dt++)
#pragma unroll
            for (int j = 0; j < 4; j++)
                crow[(size_t)(g * 4 + j) * 512 + dt * 16 + c] = f2bf(cacc[dt][j]);
    }
}

// ---------------- Kernel 3: out = LN(ctx @ W_fc + input_Q) ----------------
__global__ __launch_bounds__(256, 2) void ffn_ln_kernel(
    const unsigned short* __restrict__ ctx,
    const unsigned short* __restrict__ Wtfc,
    const float* __restrict__ inQ,
    float* __restrict__ out) {
    __shared__ float lnbuf[64][132];
    const int lane = threadIdx.x & 63;
    const int wave = threadIdx.x >> 6;
    const int g = lane >> 4, c = lane & 15;
    const int row0 = blockIdx.x * 64;

    f32x4 acc[4][2];
#pragma unroll
    for (int mt = 0; mt < 4; mt++)
#pragma unroll
        for (int nt = 0; nt < 2; nt++) acc[mt][nt] = f32x4{0.f, 0.f, 0.f, 0.f};
#pragma unroll
    for (int ks = 0; ks < 16; ks++) {
        s16x8 af[4], bf[2];
#pragma unroll
        for (int mt = 0; mt < 4; mt++) {
            const unsigned short* p = ctx + (size_t)(row0 + mt * 16 + c) * 512 + ks * 32 + 4 * g;
            af[mt] = frag8(p, p + 16);
        }
#pragma unroll
        for (int nt = 0; nt < 2; nt++) {
            const unsigned short* p = Wtfc + (size_t)(wave * 32 + nt * 16 + c) * 512 + ks * 32 + 4 * g;
            bf[nt] = frag8(p, p + 16);
        }
#pragma unroll
        for (int mt = 0; mt < 4; mt++)
#pragma unroll
            for (int nt = 0; nt < 2; nt++)
                acc[mt][nt] = __builtin_amdgcn_mfma_f32_16x16x32_bf16(af[mt], bf[nt], acc[mt][nt], 0, 0, 0);
    }
#pragma unroll
    for (int mt = 0; mt < 4; mt++)
#pragma unroll
        for (int nt = 0; nt < 2; nt++)
#pragma unroll
            for (int j = 0; j < 4; j++)
                lnbuf[mt * 16 + g * 4 + j][wave * 32 + nt * 16 + c] = acc[mt][nt][j];
    __syncthreads();

    const int r = threadIdx.x >> 2;
    const int seg = threadIdx.x & 3;
    const int grow = row0 + r;
    float x[32];
    float s1 = 0.f, s2 = 0.f;
#pragma unroll
    for (int i4 = 0; i4 < 8; i4++) {
        float4 q4 = *reinterpret_cast<const float4*>(inQ + (size_t)grow * 128 + seg * 32 + i4 * 4);
        float xs[4] = {q4.x, q4.y, q4.z, q4.w};
#pragma unroll
        for (int k = 0; k < 4; k++) {
            float xv = lnbuf[r][seg * 32 + i4 * 4 + k] + xs[k];
            x[i4 * 4 + k] = xv;
            s1 += xv;
            s2 += xv * xv;
        }
    }
    s1 += __shfl_xor(s1, 1); s1 += __shfl_xor(s1, 2);
    s2 += __shfl_xor(s2, 1); s2 += __shfl_xor(s2, 2);
    const float mu = s1 * (1.0f / 128.0f);
    const float var = s2 * (1.0f / 128.0f) - mu * mu;
    const float rs = rsqrtf(var + 1e-5f);
#pragma unroll
    for (int i = 0; i < 8; i++) {
        float4 o;
        o.x = (x[i * 4 + 0] - mu) * rs;
        o.y = (x[i * 4 + 1] - mu) * rs;
        o.z = (x[i * 4 + 2] - mu) * rs;
        o.w = (x[i * 4 + 3] - mu) * rs;
        *reinterpret_cast<float4*>(out + (size_t)grow * 128 + seg * 32 + i * 4) = o;
    }
}

// ---------------- launch ----------------
extern "C" void kernel_launch(void* const* d_in, const int* in_sizes, int n_in,
                              void* d_out, int out_size, void* d_ws, size_t ws_size,
                              hipStream_t stream) {
    const float* inQ = (const float*)d_in[0];
    const float* inK = (const float*)d_in[1];
    const float* inV = (const float*)d_in[2];
    const int*   msk = (const int*)d_in[3];
    const float* wq  = (const float*)d_in[4];
    const float* wk  = (const float*)d_in[5];
    const float* wv  = (const float*)d_in[6];
    const float* wfc = (const float*)d_in[7];

    float* out  = (float*)d_out;
    float* attn = out + (size_t)BATCH * SEQ * DMODEL;

    // ws layout (u16 units): Wtfc 64K + WQt 64K + ctx 8M + mbits 512K + Kp 8M + Vt 8M  (~51.5MB)
    unsigned short* ws   = (unsigned short*)d_ws;
    unsigned short* Wtfc = ws;
    unsigned short* WQt  = ws + 65536;
    unsigned short* ctx  = ws + 131072;
    unsigned long long* mbits = (unsigned long long*)(ws + 131072 + 8388608);
    unsigned short* Kp   = ws + 131072 + 8388608 + 524288;
    unsigned short* Vt   = Kp + 8388608;

    hipLaunchKernelGGL(prep_kernel, dim3(2064), dim3(256), 0, stream,
                       msk, mbits, wfc, wq, Wtfc, WQt);
    hipLaunchKernelGGL(proj_kernel, dim3(256, 2), dim3(512), 0, stream,
                       inK, inV, wk, wv, Kp, Vt);
    hipLaunchKernelGGL(attn_kernel, dim3(256), dim3(512), 0, stream,
                       inQ, WQt, Kp, Vt, mbits, attn, ctx);
    hipLaunchKernelGGL(ffn_ln_kernel, dim3(256), dim3(256), 0, stream, ctx, Wtfc, inQ, out);
}

// Round 18
// 221.827 us; speedup vs baseline: 2.4401x; 2.4401x over previous
//
#include <hip/hip_runtime.h>
#include <hip/hip_bf16.h>
#include <stdint.h>

#define BATCH   32
#define SEQ     512
#define DMODEL  128
#define NHEADS  8
#define DHEAD   64
#define NEGV    -1e9f

using f32x4 = __attribute__((ext_vector_type(4))) float;
using s16x8 = __attribute__((ext_vector_type(8))) short;
using u16x4 = __attribute__((ext_vector_type(4))) unsigned short;
using u16x8 = __attribute__((ext_vector_type(8))) unsigned short;

__device__ __forceinline__ unsigned short f2bf(float f) {
    union { float f; unsigned int i; } w; w.f = f;
    unsigned int u = w.i;
    u += 0x7fffu + ((u >> 16) & 1u);   // RNE
    return (unsigned short)(u >> 16);
}
__device__ __forceinline__ float bf2f(unsigned short u) {
    union { unsigned int i; float f; } w; w.i = ((unsigned int)u) << 16; return w.f;
}
__device__ __forceinline__ s16x8 fragf(const float* p0, const float* p1) {
    float4 a = *reinterpret_cast<const float4*>(p0);
    float4 b = *reinterpret_cast<const float4*>(p1);
    union { s16x8 v; unsigned short e[8]; } u;
    u.e[0] = f2bf(a.x); u.e[1] = f2bf(a.y); u.e[2] = f2bf(a.z); u.e[3] = f2bf(a.w);
    u.e[4] = f2bf(b.x); u.e[5] = f2bf(b.y); u.e[6] = f2bf(b.z); u.e[7] = f2bf(b.w);
    return u.v;
}
__device__ __forceinline__ s16x8 frag8(const unsigned short* p0, const unsigned short* p1) {
    union { s16x8 v; u16x4 h[2]; } u;
    u.h[0] = *reinterpret_cast<const u16x4*>(p0);
    u.h[1] = *reinterpret_cast<const u16x4*>(p1);
    return u.v;
}
__device__ __forceinline__ s16x8 lds_frag(const unsigned short* row_base, int col0, int swz) {
    union { s16x8 v; u16x4 h[2]; } u;
    u.h[0] = *reinterpret_cast<const u16x4*>(row_base + ((col0) ^ swz));
    u.h[1] = *reinterpret_cast<const u16x4*>(row_base + ((col0 + 16) ^ swz));
    return u.v;
}

// ---------------- Kernel 0a: transpose W_fc and W_Q (fp32 -> bf16) ----------------
__global__ void wtrans_kernel(const float* __restrict__ wfc, const float* __restrict__ wq,
                              unsigned short* __restrict__ Wtfc, unsigned short* __restrict__ WQt) {
    const int m = blockIdx.x;
    if (m < 8) {
        const int i0 = m * 8192;
        for (int i = i0 + threadIdx.x; i < i0 + 8192; i += 256) {
            int k = i >> 7, n = i & 127;
            Wtfc[(size_t)n * 512 + k] = f2bf(wfc[i]);
        }
    } else {
        const int i0 = (m - 8) * 8192;
        for (int i = i0 + threadIdx.x; i < i0 + 8192; i += 256) {
            int k = i >> 9, n = i & 511;
            WQt[(size_t)n * 128 + k] = f2bf(wq[i]);
        }
    }
}

// ---------------- Kernel 0b: mask int32 -> bitpack ----------------
__global__ void mask_bitpack_kernel(const int* __restrict__ mask,
                                    unsigned long long* __restrict__ bits) {
    const int wave = threadIdx.x >> 6, lane = threadIdx.x & 63;
    const int wid0 = (blockIdx.x * 4 + wave) * 16;
#pragma unroll
    for (int i = 0; i < 16; i++) {
        const int w = wid0 + i;
        int v = mask[(size_t)w * 64 + lane];
        unsigned long long bb = __ballot(v != 0);
        if (lane == 0) bits[w] = bb;
    }
}

// ---------------- Kernel 1: K/V projection into ws, MFMA-fragment-permuted ----------------
// Kp layout: [bh][kt 0..31][f 0..1][lane 0..63][8]  (consumer QK A-frag = one 16B load)
// Vt layout: [bh][kk 0..15][dt 0..3][lane 0..63][8] (consumer PV B-frag = one 16B load)
__global__ __launch_bounds__(512, 2) void proj_kernel(
    const float* __restrict__ inK, const float* __restrict__ inV,
    const float* __restrict__ WK, const float* __restrict__ WV,
    unsigned short* __restrict__ Kp, unsigned short* __restrict__ Vt) {
    __shared__ unsigned short Wt[64 * 128];
    const int tid = threadIdx.x;
    const int lane = tid & 63;
    const int wave = tid >> 6;
    const int g = lane >> 4, c = lane & 15;
    const int bh = blockIdx.x;
    const int b = bh >> 3, h = bh & 7;
    const int col0 = 4 * g;
    const int vmode = blockIdx.y;
    const float* X = vmode ? inV : inK;
    const float* W = vmode ? WV : WK;

    for (int i = tid; i < 8192; i += 512) {
        int k = i >> 6, d = i & 63;
        Wt[d * 128 + (k ^ ((d & 7) << 3))] = f2bf(W[(size_t)k * 512 + h * 64 + d]);
    }
    __syncthreads();

    f32x4 a4[4][4];   // [st][dt]
#pragma unroll
    for (int st = 0; st < 4; st++)
#pragma unroll
        for (int dt = 0; dt < 4; dt++) a4[st][dt] = f32x4{0.f, 0.f, 0.f, 0.f};
#pragma unroll
    for (int ks = 0; ks < 4; ks++) {
        s16x8 xf[4], wt[4];
#pragma unroll
        for (int st = 0; st < 4; st++) {
            const float* p = X + (size_t)(b * 512 + wave * 64 + st * 16 + c) * 128 + ks * 32 + col0;
            xf[st] = fragf(p, p + 16);
        }
#pragma unroll
        for (int dt = 0; dt < 4; dt++) {
            int row = dt * 16 + c;
            wt[dt] = lds_frag(Wt + row * 128, ks * 32 + col0, (row & 7) << 3);
        }
        if (!vmode) {
#pragma unroll
            for (int st = 0; st < 4; st++)
#pragma unroll
                for (int dt = 0; dt < 4; dt++)
                    a4[st][dt] = __builtin_amdgcn_mfma_f32_16x16x32_bf16(wt[dt], xf[st], a4[st][dt], 0, 0, 0);
        } else {
#pragma unroll
            for (int st = 0; st < 4; st++)
#pragma unroll
                for (int dt = 0; dt < 4; dt++)
                    a4[st][dt] = __builtin_amdgcn_mfma_f32_16x16x32_bf16(xf[st], wt[dt], a4[st][dt], 0, 0, 0);
        }
    }
    if (!vmode) {
#pragma unroll
        for (int st = 0; st < 4; st++) {
            const int kt = wave * 4 + st;
#pragma unroll
            for (int f = 0; f < 2; f++) {
                u16x8 o;
#pragma unroll
                for (int j = 0; j < 4; j++) {
                    o[j]     = f2bf(a4[st][2 * f][j]);
                    o[4 + j] = f2bf(a4[st][2 * f + 1][j]);
                }
                *reinterpret_cast<u16x8*>(Kp + ((size_t)(bh * 32 + kt) * 2 + f) * 512 + lane * 8) = o;
            }
        }
    } else {
#pragma unroll
        for (int p = 0; p < 2; p++) {
            const int kk = wave * 2 + p;
#pragma unroll
            for (int dt = 0; dt < 4; dt++) {
                u16x8 o;
#pragma unroll
                for (int j = 0; j < 4; j++) {
                    o[j]     = f2bf(a4[2 * p][dt][j]);
                    o[4 + j] = f2bf(a4[2 * p + 1][dt][j]);
                }
                *reinterpret_cast<u16x8*>(Vt + ((size_t)(bh * 16 + kk) * 4 + dt) * 512 + lane * 8) = o;
            }
        }
    }
}

// ---------------- Kernel 2: attention, single-pass, fragment-permuted K/V (round-12 exact) ----------------
// grid 2048: bid -> (bh, qc); 256 threads = 4 waves x 16 q rows. No LDS, no barriers.
__global__ __launch_bounds__(256, 2) void attn_kernel(
    const float* __restrict__ inQ,            // [b*512][128] fp32
    const unsigned short* __restrict__ WQt,   // [512][128] bf16 (W_Q^T)
    const unsigned short* __restrict__ Kp,    // [bh][kt][f][lane][8] bf16
    const unsigned short* __restrict__ Vt,    // [bh][kk][dt][lane][8] bf16
    const unsigned long long* __restrict__ mbits,
    float* __restrict__ attn_out,             // [bh][q][k] fp32
    unsigned short* __restrict__ ctx) {       // [b*512][512] bf16
    const int tid = threadIdx.x;
    const int lane = tid & 63;
    const int wave = tid >> 6;          // 0..3
    const int g = lane >> 4, c = lane & 15;
    const int col0 = 4 * g;
    const int bid = blockIdx.x;
    const int bh = (((bid & 7) * 4 + ((bid >> 3) & 3)) << 3) + ((bid >> 5) & 7);
    const int qc = bid >> 8;            // 0..7
    const int b = bh >> 3, h = bh & 7;
    const int qg = qc * 64 + wave * 16 + c;

    const unsigned short* Kb = Kp + (size_t)bh * 32768;
    const unsigned short* Vb = Vt + (size_t)bh * 32768;

    // mask bits for this q-row
    union { uint4 q[4]; unsigned short e[32]; } mb;
    {
        const unsigned short* mrow16 = (const unsigned short*)(mbits + ((size_t)b * 512 + qg) * 8);
        mb.q[0] = *reinterpret_cast<const uint4*>(mrow16);
        mb.q[1] = *reinterpret_cast<const uint4*>(mrow16 + 8);
        mb.q[2] = *reinterpret_cast<const uint4*>(mrow16 + 16);
        mb.q[3] = *reinterpret_cast<const uint4*>(mrow16 + 24);
    }

    // Q projection (global WQt, L2-hot)
    f32x4 qa[4];
#pragma unroll
    for (int dt = 0; dt < 4; dt++) qa[dt] = f32x4{0.f, 0.f, 0.f, 0.f};
    const float* Xq = inQ + ((size_t)b * 512 + qg) * 128;
#pragma unroll
    for (int ks = 0; ks < 4; ks++) {
        s16x8 xq = fragf(Xq + ks * 32 + col0, Xq + ks * 32 + col0 + 16);
#pragma unroll
        for (int dt = 0; dt < 4; dt++) {
            const unsigned short* wp = WQt + (size_t)(h * 64 + dt * 16 + c) * 128 + ks * 32 + col0;
            s16x8 wt = frag8(wp, wp + 16);
            qa[dt] = __builtin_amdgcn_mfma_f32_16x16x32_bf16(wt, xq, qa[dt], 0, 0, 0);
        }
    }
    s16x8 qf0, qf1;
    {
        union { s16x8 v; u16x4 h2[2]; } q0, q1;
#pragma unroll
        for (int j = 0; j < 4; j++) {
            q0.h2[0][j] = f2bf(qa[0][j]);
            q0.h2[1][j] = f2bf(qa[1][j]);
            q1.h2[0][j] = f2bf(qa[2][j]);
            q1.h2[1][j] = f2bf(qa[3][j]);
        }
        qf0 = q0.v; qf1 = q1.v;
    }

    // S^T = K * Q^T — fragment loads are 16B/lane fully coalesced
    f32x4 acc[32];
#pragma unroll
    for (int t = 0; t < 32; t++) acc[t] = f32x4{0.f, 0.f, 0.f, 0.f};
#pragma unroll
    for (int kt = 0; kt < 32; kt++) {
        s16x8 a0 = *reinterpret_cast<const s16x8*>(Kb + (size_t)(kt * 2 + 0) * 512 + lane * 8);
        s16x8 a1 = *reinterpret_cast<const s16x8*>(Kb + (size_t)(kt * 2 + 1) * 512 + lane * 8);
        acc[kt] = __builtin_amdgcn_mfma_f32_16x16x32_bf16(a0, qf0, acc[kt], 0, 0, 0);
        acc[kt] = __builtin_amdgcn_mfma_f32_16x16x32_bf16(a1, qf1, acc[kt], 0, 0, 0);
    }

    // scale + mask + row max
    float m = -3.0e38f;
#pragma unroll
    for (int t = 0; t < 32; t++) {
        const unsigned nib = ((unsigned)mb.e[t]) >> col0;
        float s0 = (nib & 1u) ? NEGV : acc[t][0] * 0.125f;
        float s1 = (nib & 2u) ? NEGV : acc[t][1] * 0.125f;
        float s2 = (nib & 4u) ? NEGV : acc[t][2] * 0.125f;
        float s3 = (nib & 8u) ? NEGV : acc[t][3] * 0.125f;
        acc[t] = f32x4{s0, s1, s2, s3};
        m = fmaxf(m, fmaxf(fmaxf(s0, s1), fmaxf(s2, s3)));
    }
    m = fmaxf(m, __shfl_xor(m, 16));
    m = fmaxf(m, __shfl_xor(m, 32));

    float sum = 0.f;
#pragma unroll
    for (int t = 0; t < 32; t++) {
#pragma unroll
        for (int j = 0; j < 4; j++) {
            float e = __expf(acc[t][j] - m);
            acc[t][j] = e;
            sum += e;
        }
    }
    sum += __shfl_xor(sum, 16);
    sum += __shfl_xor(sum, 32);
    const float inv = 1.0f / sum;

    float* arow = attn_out + ((size_t)bh * 512 + qg) * 512;
    f32x4 cacc[4];
#pragma unroll
    for (int dt = 0; dt < 4; dt++) cacc[dt] = f32x4{0.f, 0.f, 0.f, 0.f};

#pragma unroll
    for (int kk = 0; kk < 16; kk++) {
        f32x4 flo, fhi;
#pragma unroll
        for (int j = 0; j < 4; j++) {
            flo[j] = acc[2 * kk][j] * inv;
            fhi[j] = acc[2 * kk + 1][j] * inv;
        }
        *reinterpret_cast<f32x4*>(arow + kk * 32 + col0)      = flo;
        *reinterpret_cast<f32x4*>(arow + kk * 32 + 16 + col0) = fhi;

        union { s16x8 v; unsigned short e[8]; } pf;
        pf.e[0] = f2bf(flo[0]); pf.e[1] = f2bf(flo[1]); pf.e[2] = f2bf(flo[2]); pf.e[3] = f2bf(flo[3]);
        pf.e[4] = f2bf(fhi[0]); pf.e[5] = f2bf(fhi[1]); pf.e[6] = f2bf(fhi[2]); pf.e[7] = f2bf(fhi[3]);
#pragma unroll
        for (int dt = 0; dt < 4; dt++) {
            s16x8 vf = *reinterpret_cast<const s16x8*>(Vb + (size_t)(kk * 4 + dt) * 512 + lane * 8);
            cacc[dt] = __builtin_amdgcn_mfma_f32_16x16x32_bf16(pf.v, vf, cacc[dt], 0, 0, 0);
        }
    }

    unsigned short* crow = ctx + ((size_t)b * 512 + qc * 64 + wave * 16) * 512 + h * 64;
#pragma unroll
    for (int dt = 0; dt < 4; dt++)
#pragma unroll
        for (int j = 0; j < 4; j++)
            crow[(size_t)(g * 4 + j) * 512 + dt * 16 + c] = f2bf(cacc[dt][j]);
}

// ---------------- Kernel 3: out = LN(ctx @ W_fc + input_Q) ----------------
__global__ __launch_bounds__(256, 2) void ffn_ln_kernel(
    const unsigned short* __restrict__ ctx,
    const unsigned short* __restrict__ Wtfc,
    const float* __restrict__ inQ,
    float* __restrict__ out) {
    __shared__ float lnbuf[64][132];
    const int lane = threadIdx.x & 63;
    const int wave = threadIdx.x >> 6;
    const int g = lane >> 4, c = lane & 15;
    const int row0 = blockIdx.x * 64;

    f32x4 acc[4][2];
#pragma unroll
    for (int mt = 0; mt < 4; mt++)
#pragma unroll
        for (int nt = 0; nt < 2; nt++) acc[mt][nt] = f32x4{0.f, 0.f, 0.f, 0.f};
#pragma unroll
    for (int ks = 0; ks < 16; ks++) {
        s16x8 af[4], bf[2];
#pragma unroll
        for (int mt = 0; mt < 4; mt++) {
            const unsigned short* p = ctx + (size_t)(row0 + mt * 16 + c) * 512 + ks * 32 + 4 * g;
            af[mt] = frag8(p, p + 16);
        }
#pragma unroll
        for (int nt = 0; nt < 2; nt++) {
            const unsigned short* p = Wtfc + (size_t)(wave * 32 + nt * 16 + c) * 512 + ks * 32 + 4 * g;
            bf[nt] = frag8(p, p + 16);
        }
#pragma unroll
        for (int mt = 0; mt < 4; mt++)
#pragma unroll
            for (int nt = 0; nt < 2; nt++)
                acc[mt][nt] = __builtin_amdgcn_mfma_f32_16x16x32_bf16(af[mt], bf[nt], acc[mt][nt], 0, 0, 0);
    }
#pragma unroll
    for (int mt = 0; mt < 4; mt++)
#pragma unroll
        for (int nt = 0; nt < 2; nt++)
#pragma unroll
            for (int j = 0; j < 4; j++)
                lnbuf[mt * 16 + g * 4 + j][wave * 32 + nt * 16 + c] = acc[mt][nt][j];
    __syncthreads();

    const int r = threadIdx.x >> 2;
    const int seg = threadIdx.x & 3;
    const int grow = row0 + r;
    float x[32];
    float s1 = 0.f, s2 = 0.f;
#pragma unroll
    for (int i4 = 0; i4 < 8; i4++) {
        float4 q4 = *reinterpret_cast<const float4*>(inQ + (size_t)grow * 128 + seg * 32 + i4 * 4);
        float xs[4] = {q4.x, q4.y, q4.z, q4.w};
#pragma unroll
        for (int k = 0; k < 4; k++) {
            float xv = lnbuf[r][seg * 32 + i4 * 4 + k] + xs[k];
            x[i4 * 4 + k] = xv;
            s1 += xv;
            s2 += xv * xv;
        }
    }
    s1 += __shfl_xor(s1, 1); s1 += __shfl_xor(s1, 2);
    s2 += __shfl_xor(s2, 1); s2 += __shfl_xor(s2, 2);
    const float mu = s1 * (1.0f / 128.0f);
    const float var = s2 * (1.0f / 128.0f) - mu * mu;
    const float rs = rsqrtf(var + 1e-5f);
#pragma unroll
    for (int i = 0; i < 8; i++) {
        float4 o;
        o.x = (x[i * 4 + 0] - mu) * rs;
        o.y = (x[i * 4 + 1] - mu) * rs;
        o.z = (x[i * 4 + 2] - mu) * rs;
        o.w = (x[i * 4 + 3] - mu) * rs;
        *reinterpret_cast<float4*>(out + (size_t)grow * 128 + seg * 32 + i * 4) = o;
    }
}

// ---------------- launch ----------------
extern "C" void kernel_launch(void* const* d_in, const int* in_sizes, int n_in,
                              void* d_out, int out_size, void* d_ws, size_t ws_size,
                              hipStream_t stream) {
    const float* inQ = (const float*)d_in[0];
    const float* inK = (const float*)d_in[1];
    const float* inV = (const float*)d_in[2];
    const int*   msk = (const int*)d_in[3];
    const float* wq  = (const float*)d_in[4];
    const float* wk  = (const float*)d_in[5];
    const float* wv  = (const float*)d_in[6];
    const float* wfc = (const float*)d_in[7];

    float* out  = (float*)d_out;
    float* attn = out + (size_t)BATCH * SEQ * DMODEL;

    // ws layout (u16 units): Wtfc 64K + WQt 64K + ctx 8M + mbits 512K + Kp 8M + Vt 8M  (~51.5MB)
    unsigned short* ws   = (unsigned short*)d_ws;
    unsigned short* Wtfc = ws;
    unsigned short* WQt  = ws + 65536;
    unsigned short* ctx  = ws + 131072;
    unsigned long long* mbits = (unsigned long long*)(ws + 131072 + 8388608);
    unsigned short* Kp   = ws + 131072 + 8388608 + 524288;
    unsigned short* Vt   = Kp + 8388608;

    hipLaunchKernelGGL(wtrans_kernel, dim3(16), dim3(256), 0, stream, wfc, wq, Wtfc, WQt);
    hipLaunchKernelGGL(mask_bitpack_kernel, dim3(2048), dim3(256), 0, stream, msk, mbits);
    hipLaunchKernelGGL(proj_kernel, dim3(256, 2), dim3(512), 0, stream,
                       inK, inV, wk, wv, Kp, Vt);
    hipLaunchKernelGGL(attn_kernel, dim3(2048), dim3(256), 0, stream,
                       inQ, WQt, Kp, Vt, mbits, attn, ctx);
    hipLaunchKernelGGL(ffn_ln_kernel, dim3(256), dim3(256), 0, stream, ctx, Wtfc, inQ, out);
}